// Round 7
// baseline (58.294 us; speedup 1.0000x reference)
//
#include <hip/hip_runtime.h>

#define H 1024
#define W 1024
#define TILE 32
#define SR 40    // sum rows: TILE + 8  (halo4 coords)
#define SC 36    // sum cols: TILE + 4
#define VR 36    // vw rows:  TILE + 4
#define VC 36    // vw cols:  TILE + 4

// LDS budget: s_su 40*36*8 = 11520 B, s_vw 36*36*16 = 20736 B -> 32256 B total
// 32256 <= 163840/5 -> 5 blocks/CU (20 waves/CU). Keep VGPR <= 102.

__global__ __launch_bounds__(256)
void kuwahara_kernel(const float* __restrict__ inp, float* __restrict__ out) {
    __shared__ float2 s_su[SR][SC];   // (hsum luma, hsum luma^2), halo4 rows
    __shared__ float4 s_vw[VR][VC];   // (r, g, b, k->weight), edge-replicated

    const int tid = threadIdx.x;
    const int n  = blockIdx.z;
    const int y0 = blockIdx.y * TILE;
    const int x0 = blockIdx.x * TILE;

    const float* __restrict__ pR = inp + ((size_t)(4*n + 0) << 20);
    const float* __restrict__ pG = inp + ((size_t)(4*n + 1) << 20);
    const float* __restrict__ pB = inp + ((size_t)(4*n + 2) << 20);
    const float* __restrict__ pK = inp + ((size_t)(4*n + 3) << 20);

    const int tx  = tid & 31;   // column within tile
    const int tg  = tid >> 5;   // row-group: owns rows 4*tg .. 4*tg+3
    const int gx  = x0 + tx;
    const int pr0 = tg << 2;

    // ---- k at this thread's 4 output pixels ----
    float kc[4];
#pragma unroll
    for (int p = 0; p < 4; ++p)
        kc[p] = pK[((y0 + pr0 + p) << 10) + gx];

    // ---- stage 1 (fused): A-tasks: luma + horizontal 5-sums direct from
    // global (no luma LDS plane). B-tasks: rgbk fill of s_vw.
    // A: 360 tasks (j in [0,40), q in [0,9)); B: 324 tasks (j in [0,36), q in [0,9))
    for (int idx = tid; idx < 360 + 324; idx += 256) {
        if (idx < 360) {
            int j = idx / 9, q = idx - j * 9;
            int gy = y0 - 4 + j;
            int cy = min(max(gy, 0), H - 1);
            int gcs = x0 - 4 + (q << 2);         // first of 8 luma cols needed
            const int base = cy << 10;
            float rr[8], gg[8], bb[8];
            if (gcs >= 0 && gcs <= W - 8) {      // x-interior: 2 float4 per chan
                float4 ra = *(const float4*)(pR + base + gcs);
                float4 rb = *(const float4*)(pR + base + gcs + 4);
                float4 ga = *(const float4*)(pG + base + gcs);
                float4 gb = *(const float4*)(pG + base + gcs + 4);
                float4 ba = *(const float4*)(pB + base + gcs);
                float4 b2 = *(const float4*)(pB + base + gcs + 4);
                rr[0]=ra.x; rr[1]=ra.y; rr[2]=ra.z; rr[3]=ra.w;
                rr[4]=rb.x; rr[5]=rb.y; rr[6]=rb.z; rr[7]=rb.w;
                gg[0]=ga.x; gg[1]=ga.y; gg[2]=ga.z; gg[3]=ga.w;
                gg[4]=gb.x; gg[5]=gb.y; gg[6]=gb.z; gg[7]=gb.w;
                bb[0]=ba.x; bb[1]=ba.y; bb[2]=ba.z; bb[3]=ba.w;
                bb[4]=b2.x; bb[5]=b2.y; bb[6]=b2.z; bb[7]=b2.w;
            } else {                              // x-border: clamped scalar
#pragma unroll
                for (int e = 0; e < 8; ++e) {
                    int cx = min(max(gcs + e, 0), W - 1);
                    rr[e] = pR[base + cx]; gg[e] = pG[base + cx]; bb[e] = pB[base + cx];
                }
            }
            bool rowIn = ((unsigned)gy < (unsigned)H);
            float l[8], m[8];
#pragma unroll
            for (int e = 0; e < 8; ++e) {
                bool colIn = ((unsigned)(gcs + e) < (unsigned)W);
                float lv = (rowIn && colIn)
                    ? fmaf(0.2126f, rr[e], fmaf(0.7152f, gg[e], 0.0722f * bb[e]))
                    : 0.0f;                       // zero pad rows AND cols
                l[e] = lv; m[e] = lv * lv;
            }
            float s0 = ((l[0] + l[1]) + (l[2] + l[3])) + l[4];
            float s1 = s0 - l[0] + l[5];
            float s2 = s1 - l[1] + l[6];
            float s3 = s2 - l[2] + l[7];
            float u0 = ((m[0] + m[1]) + (m[2] + m[3])) + m[4];
            float u1 = u0 - m[0] + m[5];
            float u2 = u1 - m[1] + m[6];
            float u3 = u2 - m[2] + m[7];
            int c = q << 2;
            *(float4*)&s_su[j][c]     = make_float4(s0, u0, s1, u1);
            *(float4*)&s_su[j][c + 2] = make_float4(s2, u2, s3, u3);
        } else {
            int t = idx - 360;
            int j = t / 9, q = t - j * 9;        // j in [0,36)
            int gy = y0 - 2 + j;
            int cy = min(max(gy, 0), H - 1);
            int gcs = x0 - 2 + (q << 2);
            const int base = cy << 10;
            if (gcs >= 0 && gcs <= W - 4) {      // x-interior: vector loads
                float4 r4 = *(const float4*)(pR + base + gcs);
                float4 g4 = *(const float4*)(pG + base + gcs);
                float4 b4 = *(const float4*)(pB + base + gcs);
                float4 k4 = *(const float4*)(pK + base + gcs);
                int c = q << 2;
                s_vw[j][c+0] = make_float4(r4.x, g4.x, b4.x, k4.x);
                s_vw[j][c+1] = make_float4(r4.y, g4.y, b4.y, k4.y);
                s_vw[j][c+2] = make_float4(r4.z, g4.z, b4.z, k4.z);
                s_vw[j][c+3] = make_float4(r4.w, g4.w, b4.w, k4.w);
            } else {                              // x-border: clamped scalar
#pragma unroll
                for (int e = 0; e < 4; ++e) {
                    int cx = min(max(gcs + e, 0), W - 1);
                    s_vw[j][(q << 2) + e] =
                        make_float4(pR[base + cx], pG[base + cx],
                                    pB[base + cx], pK[base + cx]);
                }
            }
        }
    }
    __syncthreads();

    // ---- stage 3: vertical 5-sum at clamped center -> variance -> weight ----
    // 324 tasks: j2 in [0,36), q in [0,9)
    for (int idx = tid; idx < VR * 9; idx += 256) {
        int j2 = idx / 9, q = idx - j2 * 9;
        int c  = q << 2;
        int gyc = min(max(y0 - 2 + j2, 0), H - 1);  // clamped window center row
        int js  = gyc - y0 + 2;                     // window top in halo4 rows
        int g0  = x0 - 2 + c;                       // unclamped center col of e=0
        float as[4], aq[4];
        if (g0 >= 0 && g0 + 3 <= W - 1) {           // cols interior: vector path
            float4 acc0 = make_float4(0.f, 0.f, 0.f, 0.f);
            float4 acc1 = make_float4(0.f, 0.f, 0.f, 0.f);
#pragma unroll
            for (int r = 0; r < 5; ++r) {
                float4 va = *(const float4*)&s_su[js + r][c];
                float4 vb = *(const float4*)&s_su[js + r][c + 2];
                acc0.x += va.x; acc0.y += va.y; acc0.z += va.z; acc0.w += va.w;
                acc1.x += vb.x; acc1.y += vb.y; acc1.z += vb.z; acc1.w += vb.w;
            }
            as[0]=acc0.x; aq[0]=acc0.y; as[1]=acc0.z; aq[1]=acc0.w;
            as[2]=acc1.x; aq[2]=acc1.y; as[3]=acc1.z; aq[3]=acc1.w;
        } else {                                    // x-border: clamped scalar
#pragma unroll
            for (int e = 0; e < 4; ++e) {
                int is = min(max(g0 + e, 0), W - 1) - x0 + 2;
                float ss = 0.f, sq = 0.f;
#pragma unroll
                for (int r = 0; r < 5; ++r) {
                    float2 v = s_su[js + r][is];
                    ss += v.x; sq += v.y;
                }
                as[e] = ss; aq[e] = sq;
            }
        }
#pragma unroll
        for (int e = 0; e < 4; ++e) {
            float mean = as[e] * 0.04f;
            float msq  = aq[e] * 0.04f;
            float var  = fabsf(msq - mean * mean);
            float kv   = s_vw[j2][c + e].w;          // k stashed in stage 1
            s_vw[j2][c + e].w = __expf(-var * 64.0f * kv);
        }
    }
    __syncthreads();

    // ---- spatial-falloff constants (late, short live ranges) ----
    float t1[4], t4[4];
#pragma unroll
    for (int p = 0; p < 4; ++p) {
        float t = __expf(-2.56f * (1.0f - kc[p]));   // t^(dx^2+dy^2) base
        t1[p] = t;
        t4[p] = (t * t) * (t * t);
    }

    // ---- stage 4: 25-tap filter; factorized row sums shared across 4 px ----
    float accR[4], accG[4], accB[4], accW[4];
#pragma unroll
    for (int p = 0; p < 4; ++p) { accR[p] = accG[p] = accB[p] = accW[p] = 0.f; }

#pragma unroll
    for (int r = 0; r < 8; ++r) {
        const float4* row = &s_vw[pr0 + r][tx];      // single base, imm offsets
        float4 a0 = row[0], a1 = row[1], a2 = row[2], a3 = row[3], a4 = row[4];
        // partial sums by |dx|: S0 (dx=0), S1 (|dx|=1), S2 (|dx|=2)
        float S0w = a2.w;
        float S0x = a2.w * a2.x, S0y = a2.w * a2.y, S0z = a2.w * a2.z;
        float S1w = a1.w + a3.w;
        float S1x = a1.w * a1.x + a3.w * a3.x;
        float S1y = a1.w * a1.y + a3.w * a3.y;
        float S1z = a1.w * a1.z + a3.w * a3.z;
        float S2w = a0.w + a4.w;
        float S2x = a0.w * a0.x + a4.w * a4.x;
        float S2y = a0.w * a0.y + a4.w * a4.y;
        float S2z = a0.w * a0.z + a4.w * a4.z;
#pragma unroll
        for (int p = 0; p < 4; ++p) {
            const int dy = r - 2 - p;                // compile-time after unroll
            if (dy < -2 || dy > 2) continue;
            const int ady = dy < 0 ? -dy : dy;
            float rw = S0w + t1[p] * S1w + t4[p] * S2w;
            float rx = S0x + t1[p] * S1x + t4[p] * S2x;
            float ry = S0y + t1[p] * S1y + t4[p] * S2y;
            float rz = S0z + t1[p] * S1z + t4[p] * S2z;
            if (ady == 0) {
                accR[p] += rx; accG[p] += ry; accB[p] += rz; accW[p] += rw;
            } else {
                float rf = (ady == 1) ? t1[p] : t4[p];
                accR[p] += rf * rx; accG[p] += rf * ry;
                accB[p] += rf * rz; accW[p] += rf * rw;
            }
        }
    }

    float* __restrict__ oR = out + ((size_t)(3*n + 0) << 20);
    float* __restrict__ oG = out + ((size_t)(3*n + 1) << 20);
    float* __restrict__ oB = out + ((size_t)(3*n + 2) << 20);
#pragma unroll
    for (int p = 0; p < 4; ++p) {
        float4 cen = s_vw[pr0 + p + 2][tx + 2];      // center rgb from LDS
        float cb = 16.0f + kc[p] * (0.001f - 16.0f); // center boost
        accR[p] += cb * cen.x;
        accG[p] += cb * cen.y;
        accB[p] += cb * cen.z;
        accW[p] += cb;
        float inv = __builtin_amdgcn_rcpf(accW[p]);
        int off = ((y0 + pr0 + p) << 10) + gx;
        oR[off] = cen.x + kc[p] * (accR[p] * inv - cen.x);
        oG[off] = cen.y + kc[p] * (accG[p] * inv - cen.y);
        oB[off] = cen.z + kc[p] * (accB[p] * inv - cen.z);
    }
}

extern "C" void kernel_launch(void* const* d_in, const int* in_sizes, int n_in,
                              void* d_out, int out_size, void* d_ws, size_t ws_size,
                              hipStream_t stream) {
    const float* inp = (const float*)d_in[0];
    float* out = (float*)d_out;
    dim3 grid(W / TILE, H / TILE, 4);
    hipLaunchKernelGGL(kuwahara_kernel, grid, dim3(256), 0, stream, inp, out);
}